// Round 1
// baseline (2739.750 us; speedup 1.0000x reference)
//
#include <hip/hip_runtime.h>
#include <stdint.h>

#define B_    128
#define T_    512
#define PT_   536      // 24 zero-pad rows + T
#define CIN_  512
#define CINH_ 256
#define COUT_ 512
#define KS25  25

typedef __attribute__((ext_vector_type(8))) short s16x8;
typedef __attribute__((ext_vector_type(4))) float f32x4;

typedef const __attribute__((address_space(1))) void gas_t;
typedef __attribute__((address_space(3))) void las_t;

__device__ __forceinline__ short f2bf(float f) {
    union { float f; uint32_t u; } v; v.f = f;
    uint32_t r = v.u + 0x7fffu + ((v.u >> 16) & 1u);
    return (short)(r >> 16);
}
__device__ __forceinline__ float bf2f(short s) {
    union { uint32_t u; float f; } v; v.u = ((uint32_t)(uint16_t)s) << 16;
    return v.f;
}

__device__ __forceinline__ void gload16(const void* g, void* l) {
    __builtin_amdgcn_global_load_lds((gas_t*)g, (las_t*)l, 16, 0, 0);
}

// Stage a [NCHUNK/8 x 64]-bf16 tile (row stride `stride` shorts) into LDS linearly.
template<int NCHUNK>
__device__ __forceinline__ void stage_tile(const short* src, short* lds, int stride, int tid) {
    const int wbase = tid & ~63;
    #pragma unroll
    for (int c = 0; c < (NCHUNK + 255) / 256; ++c) {
        int idx = c * 256 + tid;
        if ((NCHUNK % 256 == 0) || idx < NCHUNK) {
            int row = idx >> 3;
            int col = (idx & 7) << 3;
            gload16(src + (size_t)row * stride + col, (char*)lds + (size_t)(c * 256 + wbase) * 16);
        }
    }
}

// One tap's MFMA block: acc += A_rows[d+..] * B   (K=64 split in two 16x16x32)
__device__ __forceinline__ void mfma_block(const short* Al, const short* Bl, int d,
                                           int wm, int wn, int l15, int kg, f32x4 acc[4][4]) {
    #pragma unroll
    for (int kk = 0; kk < 2; ++kk) {
        const int kof = kk * 32 + kg * 8;
        s16x8 a[4], b[4];
        #pragma unroll
        for (int m = 0; m < 4; ++m)
            a[m] = *(const s16x8*)(Al + (d + wm * 64 + m * 16 + l15) * 64 + kof);
        #pragma unroll
        for (int n = 0; n < 4; ++n)
            b[n] = *(const s16x8*)(Bl + (wn * 64 + n * 16 + l15) * 64 + kof);
        #pragma unroll
        for (int m = 0; m < 4; ++m)
            #pragma unroll
            for (int n = 0; n < 4; ++n)
                acc[m][n] = __builtin_amdgcn_mfma_f32_16x16x32_bf16(a[m], b[n], acc[m][n], 0, 0, 0);
    }
}

// Split (hi/lo) 3-term MFMA block for high-precision conv_ie
__device__ __forceinline__ void mfma_block3(const short* Ah, const short* Alo,
                                            const short* Bh, const short* Blo, int d,
                                            int wm, int wn, int l15, int kg, f32x4 acc[4][4]) {
    #pragma unroll
    for (int kk = 0; kk < 2; ++kk) {
        const int kof = kk * 32 + kg * 8;
        s16x8 ah[4], al[4], bh[4], bl[4];
        #pragma unroll
        for (int m = 0; m < 4; ++m) {
            const int ro = (d + wm * 64 + m * 16 + l15) * 64 + kof;
            ah[m] = *(const s16x8*)(Ah + ro);
            al[m] = *(const s16x8*)(Alo + ro);
        }
        #pragma unroll
        for (int n = 0; n < 4; ++n) {
            const int ro = (wn * 64 + n * 16 + l15) * 64 + kof;
            bh[n] = *(const s16x8*)(Bh + ro);
            bl[n] = *(const s16x8*)(Blo + ro);
        }
        #pragma unroll
        for (int m = 0; m < 4; ++m)
            #pragma unroll
            for (int n = 0; n < 4; ++n)
                acc[m][n] = __builtin_amdgcn_mfma_f32_16x16x32_bf16(ah[m], bh[n], acc[m][n], 0, 0, 0);
        #pragma unroll
        for (int m = 0; m < 4; ++m)
            #pragma unroll
            for (int n = 0; n < 4; ++n)
                acc[m][n] = __builtin_amdgcn_mfma_f32_16x16x32_bf16(ah[m], bl[n], acc[m][n], 0, 0, 0);
        #pragma unroll
        for (int m = 0; m < 4; ++m)
            #pragma unroll
            for (int n = 0; n < 4; ++n)
                acc[m][n] = __builtin_amdgcn_mfma_f32_16x16x32_bf16(al[m], bh[n], acc[m][n], 0, 0, 0);
    }
}

// ---------------------------------------------------------------- small kernels

__global__ void zero_pads_kernel(short* xhi, short* xlo, short* sT, float* stats) {
    int idx = blockIdx.x * 256 + threadIdx.x;
    const int NX = B_ * 24 * CIN_;
    const int NS = B_ * 24 * CINH_;
    if (idx < NX) {
        int b = idx / (24 * CIN_), r = idx % (24 * CIN_);
        xhi[(size_t)b * PT_ * CIN_ + r] = 0;
        xlo[(size_t)b * PT_ * CIN_ + r] = 0;
    }
    if (idx < NS) {
        int b = idx / (24 * CINH_), r = idx % (24 * CINH_);
        sT[(size_t)b * PT_ * CINH_ + r] = 0;
    }
    if (idx < 512) stats[idx] = 0.f;
}

// Dcls gaussian kernel -> Km[d][o][i] bf16
__global__ void build_k_kernel(const float* __restrict__ W, const float* __restrict__ P,
                               const float* __restrict__ SIG, short* __restrict__ K,
                               int O, int I, float sign) {
    int idx = blockIdx.x * 256 + threadIdx.x;
    if (idx >= O * I) return;
    float p = P[idx], sg = SIG[idx], w = fabsf(W[idx]) * sign;
    float g[KS25]; float s = 0.f;
    #pragma unroll
    for (int d = 0; d < KS25; ++d) { float z = ((float)d - p) / sg; float e = __expf(-0.5f * z * z); g[d] = e; s += e; }
    float inv = w / (s + 1e-7f);
    int OI = O * I;
    #pragma unroll
    for (int d = 0; d < KS25; ++d) K[(size_t)d * OI + idx] = f2bf(g[d] * inv);
}

__global__ void build_k_split_kernel(const float* __restrict__ W, const float* __restrict__ P,
                                     const float* __restrict__ SIG,
                                     short* __restrict__ Khi, short* __restrict__ Klo,
                                     int O, int I) {
    int idx = blockIdx.x * 256 + threadIdx.x;
    if (idx >= O * I) return;
    float p = P[idx], sg = SIG[idx], w = fabsf(W[idx]);
    float g[KS25]; float s = 0.f;
    #pragma unroll
    for (int d = 0; d < KS25; ++d) { float z = ((float)d - p) / sg; float e = __expf(-0.5f * z * z); g[d] = e; s += e; }
    float inv = w / (s + 1e-7f);
    int OI = O * I;
    #pragma unroll
    for (int d = 0; d < KS25; ++d) {
        float v = g[d] * inv;
        short hi = f2bf(v);
        Khi[(size_t)d * OI + idx] = hi;
        Klo[(size_t)d * OI + idx] = f2bf(v - bf2f(hi));
    }
}

// x [B][C][T] f32 -> xhi/xlo [B][PT][C] bf16 (rows shifted +24)
__global__ void transpose_split_kernel(const float* __restrict__ x,
                                       short* __restrict__ xhi, short* __restrict__ xlo) {
    __shared__ float tile[32][33];
    int b = blockIdx.x, cb = blockIdx.y, tb = blockIdx.z;
    int tx = threadIdx.x, ty = threadIdx.y;
    #pragma unroll
    for (int r = 0; r < 4; ++r) {
        int c = cb * 32 + ty + r * 8;
        int t = tb * 32 + tx;
        tile[ty + r * 8][tx] = x[((size_t)b * CIN_ + c) * T_ + t];
    }
    __syncthreads();
    #pragma unroll
    for (int r = 0; r < 4; ++r) {
        int t = tb * 32 + ty + r * 8;
        int c = cb * 32 + tx;
        float v = tile[tx][ty + r * 8];
        short hi = f2bf(v);
        size_t o = ((size_t)b * PT_ + 24 + t) * CIN_ + c;
        xhi[o] = hi;
        xlo[o] = f2bf(v - bf2f(hi));
    }
}

__global__ void bn_stats_kernel(const float* __restrict__ h, float* __restrict__ stats) {
    int c = threadIdx.x;
    int r0 = blockIdx.x * 128;
    float s = 0.f, s2 = 0.f;
    for (int r = 0; r < 128; ++r) {
        float v = h[(size_t)(r0 + r) * CINH_ + c];
        s += v; s2 += v * v;
    }
    atomicAdd(&stats[c], s);
    atomicAdd(&stats[256 + c], s2);
}

__global__ void bn_final_kernel(const float* __restrict__ stats, const float* __restrict__ gamma,
                                const float* __restrict__ beta, float* __restrict__ bnp) {
    int c = threadIdx.x;
    const float invN = 1.f / (float)(B_ * T_);
    float mean = stats[c] * invN;
    float var = stats[256 + c] * invN - mean * mean;
    float sc = gamma[c] * rsqrtf(var + 1e-5f);
    bnp[c] = sc;
    bnp[256 + c] = beta[c] - mean * sc;
}

// LIF scan: tau=2 (v = 0.5v + h'), vth=1, hard reset; writes spikes bf16 into sT rows 24..
__global__ __launch_bounds__(64) void lif_kernel(const float* __restrict__ h,
                                                 const float* __restrict__ bnp,
                                                 short* __restrict__ sT) {
    int bidx = blockIdx.x;
    int b = bidx >> 2;
    int c = (bidx & 3) * 64 + threadIdx.x;
    float sc = bnp[c], sh = bnp[256 + c];
    const float* hp = h + (size_t)b * T_ * CINH_ + c;
    short* sp = sT + ((size_t)b * PT_ + 24) * CINH_ + c;
    float v = 0.f;
    #pragma unroll 4
    for (int t = 0; t < T_; ++t) {
        float hv = hp[(size_t)t * CINH_] * sc + sh;
        v = 0.5f * v + hv;
        bool spike = (v >= 1.0f);
        sp[(size_t)t * CINH_] = spike ? (short)0x3F80 : (short)0;
        v = spike ? 0.f : v;
    }
}

// ---------------------------------------------------------------- conv GEMMs

// h = conv(x, K_ie) in split precision. grid = (B*T/128) * (CINH/128)
__global__ __launch_bounds__(256, 2)
void conv_ie_kernel(const short* __restrict__ xhi, const short* __restrict__ xlo,
                    const short* __restrict__ Khi, const short* __restrict__ Klo,
                    float* __restrict__ h) {
    __shared__ short Ah[152 * 64], Alo[152 * 64], Bh[128 * 64], Blo[128 * 64];
    const int tid = threadIdx.x;
    const int wave = tid >> 6, lane = tid & 63;
    const int wm = wave >> 1, wn = wave & 1;
    const int l15 = lane & 15, kg = lane >> 4;
    const int bid = blockIdx.x;
    const int nt = bid & 1, mt = bid >> 1;
    const int b = mt >> 2, t0 = (mt & 3) << 7;
    const int o0 = nt << 7;

    f32x4 acc[4][4];
    const f32x4 zero = {0.f, 0.f, 0.f, 0.f};
    #pragma unroll
    for (int m = 0; m < 4; ++m)
        #pragma unroll
        for (int n = 0; n < 4; ++n) acc[m][n] = zero;

    const short* A0h = xhi + ((size_t)b * PT_ + t0) * CIN_;
    const short* A0l = xlo + ((size_t)b * PT_ + t0) * CIN_;
    const short* K0h = Khi + (size_t)o0 * CIN_;
    const short* K0l = Klo + (size_t)o0 * CIN_;

    #pragma unroll 1
    for (int ci0 = 0; ci0 < CIN_; ci0 += 64) {
        stage_tile<1216>(A0h + ci0, Ah, CIN_, tid);
        stage_tile<1216>(A0l + ci0, Alo, CIN_, tid);
        #pragma unroll 1
        for (int d = 0; d < KS25; ++d) {
            stage_tile<1024>(K0h + (size_t)d * CINH_ * CIN_ + ci0, Bh, CIN_, tid);
            stage_tile<1024>(K0l + (size_t)d * CINH_ * CIN_ + ci0, Blo, CIN_, tid);
            __syncthreads();
            mfma_block3(Ah, Alo, Bh, Blo, d, wm, wn, l15, kg, acc);
            __syncthreads();
        }
    }
    // epilogue: h[b][t][c] (c contiguous)
    #pragma unroll
    for (int m = 0; m < 4; ++m) {
        const int trb = t0 + wm * 64 + m * 16 + kg * 4;
        #pragma unroll
        for (int n = 0; n < 4; ++n) {
            const int c = o0 + wn * 64 + n * 16 + l15;
            f32x4 v = acc[m][n];
            h[((size_t)b * T_ + trb + 0) * CINH_ + c] = v.x;
            h[((size_t)b * T_ + trb + 1) * CINH_ + c] = v.y;
            h[((size_t)b * T_ + trb + 2) * CINH_ + c] = v.z;
            h[((size_t)b * T_ + trb + 3) * CINH_ + c] = v.w;
        }
    }
}

// out = conv(x,K_ee) + conv(s,K_oi) + bias, written as [B][O][T]. grid = (B*T/128)*(COUT/128)
__global__ __launch_bounds__(256, 2)
void conv_out_kernel(const short* __restrict__ xT, const short* __restrict__ sT,
                     const short* __restrict__ Kee, const short* __restrict__ Koi,
                     const float* __restrict__ bias, float* __restrict__ out) {
    __shared__ short Al[152 * 64];
    __shared__ short Bl[128 * 64];
    const int tid = threadIdx.x;
    const int wave = tid >> 6, lane = tid & 63;
    const int wm = wave >> 1, wn = wave & 1;
    const int l15 = lane & 15, kg = lane >> 4;
    const int bid = blockIdx.x;
    const int nt = bid & 3, mt = bid >> 2;
    const int b = mt >> 2, t0 = (mt & 3) << 7;
    const int o0 = nt << 7;

    f32x4 acc[4][4];
    const f32x4 zero = {0.f, 0.f, 0.f, 0.f};
    #pragma unroll
    for (int m = 0; m < 4; ++m)
        #pragma unroll
        for (int n = 0; n < 4; ++n) acc[m][n] = zero;

    {   // phase 1: x * K_ee (CA = 512)
        const short* A0 = xT + ((size_t)b * PT_ + t0) * CIN_;
        const short* K0 = Kee + (size_t)o0 * CIN_;
        #pragma unroll 1
        for (int ci0 = 0; ci0 < CIN_; ci0 += 64) {
            stage_tile<1216>(A0 + ci0, Al, CIN_, tid);
            #pragma unroll 1
            for (int d = 0; d < KS25; ++d) {
                stage_tile<1024>(K0 + (size_t)d * COUT_ * CIN_ + ci0, Bl, CIN_, tid);
                __syncthreads();
                mfma_block(Al, Bl, d, wm, wn, l15, kg, acc);
                __syncthreads();
            }
        }
    }
    {   // phase 2: s * K_oi (CA = 256)
        const short* A0 = sT + ((size_t)b * PT_ + t0) * CINH_;
        const short* K0 = Koi + (size_t)o0 * CINH_;
        #pragma unroll 1
        for (int ci0 = 0; ci0 < CINH_; ci0 += 64) {
            stage_tile<1216>(A0 + ci0, Al, CINH_, tid);
            #pragma unroll 1
            for (int d = 0; d < KS25; ++d) {
                stage_tile<1024>(K0 + (size_t)d * COUT_ * CINH_ + ci0, Bl, CINH_, tid);
                __syncthreads();
                mfma_block(Al, Bl, d, wm, wn, l15, kg, acc);
                __syncthreads();
            }
        }
    }
    // epilogue: out[b][o][t] + bias, float4 along t
    #pragma unroll
    for (int n = 0; n < 4; ++n) {
        const int o = o0 + wn * 64 + n * 16 + l15;
        const float bv = bias[o];
        #pragma unroll
        for (int m = 0; m < 4; ++m) {
            const int tr = t0 + wm * 64 + m * 16 + kg * 4;
            f32x4 v = acc[m][n];
            v.x += bv; v.y += bv; v.z += bv; v.w += bv;
            *(f32x4*)&out[((size_t)b * COUT_ + o) * T_ + tr] = v;
        }
    }
}

// ---------------------------------------------------------------- launch

extern "C" void kernel_launch(void* const* d_in, const int* in_sizes, int n_in,
                              void* d_out, int out_size, void* d_ws, size_t ws_size,
                              hipStream_t stream) {
    const float* x     = (const float*)d_in[0];
    const float* W_ie  = (const float*)d_in[1];
    const float* P_ie  = (const float*)d_in[2];
    const float* S_ie  = (const float*)d_in[3];
    const float* W_oi  = (const float*)d_in[4];
    const float* P_oi  = (const float*)d_in[5];
    const float* S_oi  = (const float*)d_in[6];
    const float* W_ee  = (const float*)d_in[7];
    const float* P_ee  = (const float*)d_in[8];
    const float* S_ee  = (const float*)d_in[9];
    const float* gamma = (const float*)d_in[10];
    const float* beta  = (const float*)d_in[11];
    const float* bias  = (const float*)d_in[12];
    float* out = (float*)d_out;

    char* w = (char*)d_ws;
    size_t off = 0;
    auto take = [&](size_t n) { char* p = w + off; off += (n + 255) & ~(size_t)255; return p; };

    short* xhi   = (short*)take((size_t)B_ * PT_ * CIN_ * 2);
    short* xlo   = (short*)take((size_t)B_ * PT_ * CIN_ * 2);
    short* sT    = (short*)take((size_t)B_ * PT_ * CINH_ * 2);
    short* Kie_h = (short*)take((size_t)KS25 * CINH_ * CIN_ * 2);
    short* Kie_l = (short*)take((size_t)KS25 * CINH_ * CIN_ * 2);
    short* Koi   = (short*)take((size_t)KS25 * COUT_ * CINH_ * 2);
    short* Kee   = (short*)take((size_t)KS25 * COUT_ * CIN_ * 2);
    float* h     = (float*)take((size_t)B_ * T_ * CINH_ * 4);
    float* stats = (float*)take(512 * 4);
    float* bnp   = (float*)take(512 * 4);

    zero_pads_kernel<<<6144, 256, 0, stream>>>(xhi, xlo, sT, stats);
    build_k_split_kernel<<<(CINH_ * CIN_ + 255) / 256, 256, 0, stream>>>(W_ie, P_ie, S_ie, Kie_h, Kie_l, CINH_, CIN_);
    build_k_kernel<<<(COUT_ * CINH_ + 255) / 256, 256, 0, stream>>>(W_oi, P_oi, S_oi, Koi, COUT_, CINH_, -1.f);
    build_k_kernel<<<(COUT_ * CIN_ + 255) / 256, 256, 0, stream>>>(W_ee, P_ee, S_ee, Kee, COUT_, CIN_, 1.f);
    transpose_split_kernel<<<dim3(B_, CIN_ / 32, T_ / 32), dim3(32, 8), 0, stream>>>(x, xhi, xlo);
    conv_ie_kernel<<<(B_ * T_ / 128) * (CINH_ / 128), 256, 0, stream>>>(xhi, xlo, Kie_h, Kie_l, h);
    bn_stats_kernel<<<512, 256, 0, stream>>>(h, stats);
    bn_final_kernel<<<1, 256, 0, stream>>>(stats, gamma, beta, bnp);
    lif_kernel<<<B_ * (CINH_ / 64), 64, 0, stream>>>(h, bnp, sT);
    conv_out_kernel<<<(B_ * T_ / 128) * (COUT_ / 128), 256, 0, stream>>>(xhi, sT, Kee, Koi, bias, out);
}

// Round 2
// 2054.502 us; speedup vs baseline: 1.3335x; 1.3335x over previous
//
#include <hip/hip_runtime.h>
#include <stdint.h>

#define B_    128
#define T_    512
#define PT_   536      // 24 zero-pad rows + T
#define CIN_  512
#define CINH_ 256
#define COUT_ 512
#define KS25  25

typedef __attribute__((ext_vector_type(8))) short s16x8;
typedef __attribute__((ext_vector_type(4))) float f32x4;

typedef const __attribute__((address_space(1))) void gas_t;
typedef __attribute__((address_space(3))) void las_t;

__device__ __forceinline__ short f2bf(float f) {
    union { float f; uint32_t u; } v; v.f = f;
    uint32_t r = v.u + 0x7fffu + ((v.u >> 16) & 1u);
    return (short)(r >> 16);
}
__device__ __forceinline__ float bf2f(short s) {
    union { uint32_t u; float f; } v; v.u = ((uint32_t)(uint16_t)s) << 16;
    return v.f;
}

__device__ __forceinline__ void gload16(const void* g, void* l) {
    __builtin_amdgcn_global_load_lds((gas_t*)g, (las_t*)l, 16, 0, 0);
}

// Stage a [NCHUNK/8 x 64]-bf16 tile (row stride `stride` shorts) into LDS.
// LDS dest is LINEAR (global_load_lds requirement); the global SOURCE column
// is XOR-swizzled (col16 ^= row&7) so that a matching XOR on the read side
// yields bank-conflict-free ds_read_b128 (T2, both-sides rule #21).
template<int NCHUNK>
__device__ __forceinline__ void stage_tile(const short* src, short* lds, int stride, int tid) {
    const int wbase = tid & ~63;
    #pragma unroll
    for (int c = 0; c < (NCHUNK + 255) / 256; ++c) {
        int idx = c * 256 + tid;
        if ((NCHUNK % 256 == 0) || idx < NCHUNK) {
            int row = idx >> 3;
            int col = ((idx & 7) ^ (row & 7)) << 3;   // inverse-swizzled source
            gload16(src + (size_t)row * stride + col, (char*)lds + (size_t)(c * 256 + wbase) * 16);
        }
    }
}

// One tap's MFMA block: acc += A_rows[d+..] * B   (K=64 split in two 16x16x32)
// Reads apply the same XOR swizzle: logical 16B-slot k at row r lives at slot k^(r&7).
__device__ __forceinline__ void mfma_block(const short* Al, const short* Bl, int d,
                                           int wm, int wn, int l15, int kg, f32x4 acc[4][4]) {
    const int xa = (d + l15) & 7;     // rowA&7 is invariant across m (m*16, wm*64 are mult of 8)
    const int xb = l15 & 7;           // rowB&7 invariant across n
    #pragma unroll
    for (int kk = 0; kk < 2; ++kk) {
        const int ks = kk * 4 + kg;                 // logical 16B slot 0..7
        const int ka = (ks ^ xa) << 3;              // swizzled short offset
        const int kb = (ks ^ xb) << 3;
        s16x8 a[4], b[4];
        #pragma unroll
        for (int m = 0; m < 4; ++m)
            a[m] = *(const s16x8*)(Al + (d + wm * 64 + m * 16 + l15) * 64 + ka);
        #pragma unroll
        for (int n = 0; n < 4; ++n)
            b[n] = *(const s16x8*)(Bl + (wn * 64 + n * 16 + l15) * 64 + kb);
        #pragma unroll
        for (int m = 0; m < 4; ++m)
            #pragma unroll
            for (int n = 0; n < 4; ++n)
                acc[m][n] = __builtin_amdgcn_mfma_f32_16x16x32_bf16(a[m], b[n], acc[m][n], 0, 0, 0);
    }
}

// Split (hi/lo) 3-term MFMA block for high-precision conv_ie
__device__ __forceinline__ void mfma_block3(const short* Ah, const short* Alo,
                                            const short* Bh, const short* Blo, int d,
                                            int wm, int wn, int l15, int kg, f32x4 acc[4][4]) {
    const int xa = (d + l15) & 7;
    const int xb = l15 & 7;
    #pragma unroll
    for (int kk = 0; kk < 2; ++kk) {
        const int ks = kk * 4 + kg;
        const int ka = (ks ^ xa) << 3;
        const int kb = (ks ^ xb) << 3;
        s16x8 ah[4], al[4], bh[4], bl[4];
        #pragma unroll
        for (int m = 0; m < 4; ++m) {
            const int ro = (d + wm * 64 + m * 16 + l15) * 64 + ka;
            ah[m] = *(const s16x8*)(Ah + ro);
            al[m] = *(const s16x8*)(Alo + ro);
        }
        #pragma unroll
        for (int n = 0; n < 4; ++n) {
            const int ro = (wn * 64 + n * 16 + l15) * 64 + kb;
            bh[n] = *(const s16x8*)(Bh + ro);
            bl[n] = *(const s16x8*)(Blo + ro);
        }
        #pragma unroll
        for (int m = 0; m < 4; ++m)
            #pragma unroll
            for (int n = 0; n < 4; ++n)
                acc[m][n] = __builtin_amdgcn_mfma_f32_16x16x32_bf16(ah[m], bh[n], acc[m][n], 0, 0, 0);
        #pragma unroll
        for (int m = 0; m < 4; ++m)
            #pragma unroll
            for (int n = 0; n < 4; ++n)
                acc[m][n] = __builtin_amdgcn_mfma_f32_16x16x32_bf16(ah[m], bl[n], acc[m][n], 0, 0, 0);
        #pragma unroll
        for (int m = 0; m < 4; ++m)
            #pragma unroll
            for (int n = 0; n < 4; ++n)
                acc[m][n] = __builtin_amdgcn_mfma_f32_16x16x32_bf16(al[m], bh[n], acc[m][n], 0, 0, 0);
    }
}

// ---------------------------------------------------------------- small kernels

__global__ void zero_pads_kernel(short* xhi, short* xlo, short* sT, float* stats) {
    int idx = blockIdx.x * 256 + threadIdx.x;
    const int NX = B_ * 24 * CIN_;
    const int NS = B_ * 24 * CINH_;
    if (idx < NX) {
        int b = idx / (24 * CIN_), r = idx % (24 * CIN_);
        xhi[(size_t)b * PT_ * CIN_ + r] = 0;
        xlo[(size_t)b * PT_ * CIN_ + r] = 0;
    }
    if (idx < NS) {
        int b = idx / (24 * CINH_), r = idx % (24 * CINH_);
        sT[(size_t)b * PT_ * CINH_ + r] = 0;
    }
    if (idx < 512) stats[idx] = 0.f;
}

// Dcls gaussian kernel -> Km[d][o][i] bf16
__global__ void build_k_kernel(const float* __restrict__ W, const float* __restrict__ P,
                               const float* __restrict__ SIG, short* __restrict__ K,
                               int O, int I, float sign) {
    int idx = blockIdx.x * 256 + threadIdx.x;
    if (idx >= O * I) return;
    float p = P[idx], sg = SIG[idx], w = fabsf(W[idx]) * sign;
    float g[KS25]; float s = 0.f;
    #pragma unroll
    for (int d = 0; d < KS25; ++d) { float z = ((float)d - p) / sg; float e = __expf(-0.5f * z * z); g[d] = e; s += e; }
    float inv = w / (s + 1e-7f);
    int OI = O * I;
    #pragma unroll
    for (int d = 0; d < KS25; ++d) K[(size_t)d * OI + idx] = f2bf(g[d] * inv);
}

__global__ void build_k_split_kernel(const float* __restrict__ W, const float* __restrict__ P,
                                     const float* __restrict__ SIG,
                                     short* __restrict__ Khi, short* __restrict__ Klo,
                                     int O, int I) {
    int idx = blockIdx.x * 256 + threadIdx.x;
    if (idx >= O * I) return;
    float p = P[idx], sg = SIG[idx], w = fabsf(W[idx]);
    float g[KS25]; float s = 0.f;
    #pragma unroll
    for (int d = 0; d < KS25; ++d) { float z = ((float)d - p) / sg; float e = __expf(-0.5f * z * z); g[d] = e; s += e; }
    float inv = w / (s + 1e-7f);
    int OI = O * I;
    #pragma unroll
    for (int d = 0; d < KS25; ++d) {
        float v = g[d] * inv;
        short hi = f2bf(v);
        Khi[(size_t)d * OI + idx] = hi;
        Klo[(size_t)d * OI + idx] = f2bf(v - bf2f(hi));
    }
}

// x [B][C][T] f32 -> xhi/xlo [B][PT][C] bf16 (rows shifted +24)
__global__ void transpose_split_kernel(const float* __restrict__ x,
                                       short* __restrict__ xhi, short* __restrict__ xlo) {
    __shared__ float tile[32][33];
    int b = blockIdx.x, cb = blockIdx.y, tb = blockIdx.z;
    int tx = threadIdx.x, ty = threadIdx.y;
    #pragma unroll
    for (int r = 0; r < 4; ++r) {
        int c = cb * 32 + ty + r * 8;
        int t = tb * 32 + tx;
        tile[ty + r * 8][tx] = x[((size_t)b * CIN_ + c) * T_ + t];
    }
    __syncthreads();
    #pragma unroll
    for (int r = 0; r < 4; ++r) {
        int t = tb * 32 + ty + r * 8;
        int c = cb * 32 + tx;
        float v = tile[tx][ty + r * 8];
        short hi = f2bf(v);
        size_t o = ((size_t)b * PT_ + 24 + t) * CIN_ + c;
        xhi[o] = hi;
        xlo[o] = f2bf(v - bf2f(hi));
    }
}

__global__ void bn_stats_kernel(const float* __restrict__ h, float* __restrict__ stats) {
    int c = threadIdx.x;
    int r0 = blockIdx.x * 128;
    float s = 0.f, s2 = 0.f;
    for (int r = 0; r < 128; ++r) {
        float v = h[(size_t)(r0 + r) * CINH_ + c];
        s += v; s2 += v * v;
    }
    atomicAdd(&stats[c], s);
    atomicAdd(&stats[256 + c], s2);
}

__global__ void bn_final_kernel(const float* __restrict__ stats, const float* __restrict__ gamma,
                                const float* __restrict__ beta, float* __restrict__ bnp) {
    int c = threadIdx.x;
    const float invN = 1.f / (float)(B_ * T_);
    float mean = stats[c] * invN;
    float var = stats[256 + c] * invN - mean * mean;
    float sc = gamma[c] * rsqrtf(var + 1e-5f);
    bnp[c] = sc;
    bnp[256 + c] = beta[c] - mean * sc;
}

// LIF scan: tau=2 (v = 0.5v + h'), vth=1, hard reset; writes spikes bf16 into sT rows 24..
__global__ __launch_bounds__(64) void lif_kernel(const float* __restrict__ h,
                                                 const float* __restrict__ bnp,
                                                 short* __restrict__ sT) {
    int bidx = blockIdx.x;
    int b = bidx >> 2;
    int c = (bidx & 3) * 64 + threadIdx.x;
    float sc = bnp[c], sh = bnp[256 + c];
    const float* hp = h + (size_t)b * T_ * CINH_ + c;
    short* sp = sT + ((size_t)b * PT_ + 24) * CINH_ + c;
    float v = 0.f;
    #pragma unroll 4
    for (int t = 0; t < T_; ++t) {
        float hv = hp[(size_t)t * CINH_] * sc + sh;
        v = 0.5f * v + hv;
        bool spike = (v >= 1.0f);
        sp[(size_t)t * CINH_] = spike ? (short)0x3F80 : (short)0;
        v = spike ? 0.f : v;
    }
}

// ---------------------------------------------------------------- conv GEMMs

// h = conv(x, K_ie) in split precision. grid = (B*T/128) * (CINH/128)
__global__ __launch_bounds__(256, 2)
void conv_ie_kernel(const short* __restrict__ xhi, const short* __restrict__ xlo,
                    const short* __restrict__ Khi, const short* __restrict__ Klo,
                    float* __restrict__ h) {
    __shared__ short Ah[152 * 64], Alo[152 * 64], Bh[128 * 64], Blo[128 * 64];
    const int tid = threadIdx.x;
    const int wave = tid >> 6, lane = tid & 63;
    const int wm = wave >> 1, wn = wave & 1;
    const int l15 = lane & 15, kg = lane >> 4;
    const int bid = blockIdx.x;
    const int nt = bid & 1, mt = bid >> 1;
    const int b = mt >> 2, t0 = (mt & 3) << 7;
    const int o0 = nt << 7;

    f32x4 acc[4][4];
    const f32x4 zero = {0.f, 0.f, 0.f, 0.f};
    #pragma unroll
    for (int m = 0; m < 4; ++m)
        #pragma unroll
        for (int n = 0; n < 4; ++n) acc[m][n] = zero;

    const short* A0h = xhi + ((size_t)b * PT_ + t0) * CIN_;
    const short* A0l = xlo + ((size_t)b * PT_ + t0) * CIN_;
    const short* K0h = Khi + (size_t)o0 * CIN_;
    const short* K0l = Klo + (size_t)o0 * CIN_;

    #pragma unroll 1
    for (int ci0 = 0; ci0 < CIN_; ci0 += 64) {
        stage_tile<1216>(A0h + ci0, Ah, CIN_, tid);
        stage_tile<1216>(A0l + ci0, Alo, CIN_, tid);
        #pragma unroll 1
        for (int d = 0; d < KS25; ++d) {
            stage_tile<1024>(K0h + (size_t)d * CINH_ * CIN_ + ci0, Bh, CIN_, tid);
            stage_tile<1024>(K0l + (size_t)d * CINH_ * CIN_ + ci0, Blo, CIN_, tid);
            __syncthreads();
            mfma_block3(Ah, Alo, Bh, Blo, d, wm, wn, l15, kg, acc);
            __syncthreads();
        }
    }
    // epilogue: h[b][t][c] (c contiguous)
    #pragma unroll
    for (int m = 0; m < 4; ++m) {
        const int trb = t0 + wm * 64 + m * 16 + kg * 4;
        #pragma unroll
        for (int n = 0; n < 4; ++n) {
            const int c = o0 + wn * 64 + n * 16 + l15;
            f32x4 v = acc[m][n];
            h[((size_t)b * T_ + trb + 0) * CINH_ + c] = v.x;
            h[((size_t)b * T_ + trb + 1) * CINH_ + c] = v.y;
            h[((size_t)b * T_ + trb + 2) * CINH_ + c] = v.z;
            h[((size_t)b * T_ + trb + 3) * CINH_ + c] = v.w;
        }
    }
}

// out = conv(x,K_ee) + conv(s,K_oi) + bias, written as [B][O][T]. grid = (B*T/128)*(COUT/128)
__global__ __launch_bounds__(256, 2)
void conv_out_kernel(const short* __restrict__ xT, const short* __restrict__ sT,
                     const short* __restrict__ Kee, const short* __restrict__ Koi,
                     const float* __restrict__ bias, float* __restrict__ out) {
    __shared__ short Al[152 * 64];
    __shared__ short Bl[128 * 64];
    const int tid = threadIdx.x;
    const int wave = tid >> 6, lane = tid & 63;
    const int wm = wave >> 1, wn = wave & 1;
    const int l15 = lane & 15, kg = lane >> 4;
    const int bid = blockIdx.x;
    const int nt = bid & 3, mt = bid >> 2;
    const int b = mt >> 2, t0 = (mt & 3) << 7;
    const int o0 = nt << 7;

    f32x4 acc[4][4];
    const f32x4 zero = {0.f, 0.f, 0.f, 0.f};
    #pragma unroll
    for (int m = 0; m < 4; ++m)
        #pragma unroll
        for (int n = 0; n < 4; ++n) acc[m][n] = zero;

    {   // phase 1: x * K_ee (CA = 512)
        const short* A0 = xT + ((size_t)b * PT_ + t0) * CIN_;
        const short* K0 = Kee + (size_t)o0 * CIN_;
        #pragma unroll 1
        for (int ci0 = 0; ci0 < CIN_; ci0 += 64) {
            stage_tile<1216>(A0 + ci0, Al, CIN_, tid);
            #pragma unroll 1
            for (int d = 0; d < KS25; ++d) {
                stage_tile<1024>(K0 + (size_t)d * COUT_ * CIN_ + ci0, Bl, CIN_, tid);
                __syncthreads();
                mfma_block(Al, Bl, d, wm, wn, l15, kg, acc);
                __syncthreads();
            }
        }
    }
    {   // phase 2: s * K_oi (CA = 256)
        const short* A0 = sT + ((size_t)b * PT_ + t0) * CINH_;
        const short* K0 = Koi + (size_t)o0 * CINH_;
        #pragma unroll 1
        for (int ci0 = 0; ci0 < CINH_; ci0 += 64) {
            stage_tile<1216>(A0 + ci0, Al, CINH_, tid);
            #pragma unroll 1
            for (int d = 0; d < KS25; ++d) {
                stage_tile<1024>(K0 + (size_t)d * COUT_ * CINH_ + ci0, Bl, CINH_, tid);
                __syncthreads();
                mfma_block(Al, Bl, d, wm, wn, l15, kg, acc);
                __syncthreads();
            }
        }
    }
    // epilogue: out[b][o][t] + bias, float4 along t
    #pragma unroll
    for (int n = 0; n < 4; ++n) {
        const int o = o0 + wn * 64 + n * 16 + l15;
        const float bv = bias[o];
        #pragma unroll
        for (int m = 0; m < 4; ++m) {
            const int tr = t0 + wm * 64 + m * 16 + kg * 4;
            f32x4 v = acc[m][n];
            v.x += bv; v.y += bv; v.z += bv; v.w += bv;
            *(f32x4*)&out[((size_t)b * COUT_ + o) * T_ + tr] = v;
        }
    }
}

// ---------------------------------------------------------------- launch

extern "C" void kernel_launch(void* const* d_in, const int* in_sizes, int n_in,
                              void* d_out, int out_size, void* d_ws, size_t ws_size,
                              hipStream_t stream) {
    const float* x     = (const float*)d_in[0];
    const float* W_ie  = (const float*)d_in[1];
    const float* P_ie  = (const float*)d_in[2];
    const float* S_ie  = (const float*)d_in[3];
    const float* W_oi  = (const float*)d_in[4];
    const float* P_oi  = (const float*)d_in[5];
    const float* S_oi  = (const float*)d_in[6];
    const float* W_ee  = (const float*)d_in[7];
    const float* P_ee  = (const float*)d_in[8];
    const float* S_ee  = (const float*)d_in[9];
    const float* gamma = (const float*)d_in[10];
    const float* beta  = (const float*)d_in[11];
    const float* bias  = (const float*)d_in[12];
    float* out = (float*)d_out;

    char* w = (char*)d_ws;
    size_t off = 0;
    auto take = [&](size_t n) { char* p = w + off; off += (n + 255) & ~(size_t)255; return p; };

    short* xhi   = (short*)take((size_t)B_ * PT_ * CIN_ * 2);
    short* xlo   = (short*)take((size_t)B_ * PT_ * CIN_ * 2);
    short* sT    = (short*)take((size_t)B_ * PT_ * CINH_ * 2);
    short* Kie_h = (short*)take((size_t)KS25 * CINH_ * CIN_ * 2);
    short* Kie_l = (short*)take((size_t)KS25 * CINH_ * CIN_ * 2);
    short* Koi   = (short*)take((size_t)KS25 * COUT_ * CINH_ * 2);
    short* Kee   = (short*)take((size_t)KS25 * COUT_ * CIN_ * 2);
    float* h     = (float*)take((size_t)B_ * T_ * CINH_ * 4);
    float* stats = (float*)take(512 * 4);
    float* bnp   = (float*)take(512 * 4);

    zero_pads_kernel<<<6144, 256, 0, stream>>>(xhi, xlo, sT, stats);
    build_k_split_kernel<<<(CINH_ * CIN_ + 255) / 256, 256, 0, stream>>>(W_ie, P_ie, S_ie, Kie_h, Kie_l, CINH_, CIN_);
    build_k_kernel<<<(COUT_ * CINH_ + 255) / 256, 256, 0, stream>>>(W_oi, P_oi, S_oi, Koi, COUT_, CINH_, -1.f);
    build_k_kernel<<<(COUT_ * CIN_ + 255) / 256, 256, 0, stream>>>(W_ee, P_ee, S_ee, Kee, COUT_, CIN_, 1.f);
    transpose_split_kernel<<<dim3(B_, CIN_ / 32, T_ / 32), dim3(32, 8), 0, stream>>>(x, xhi, xlo);
    conv_ie_kernel<<<(B_ * T_ / 128) * (CINH_ / 128), 256, 0, stream>>>(xhi, xlo, Kie_h, Kie_l, h);
    bn_stats_kernel<<<512, 256, 0, stream>>>(h, stats);
    bn_final_kernel<<<1, 256, 0, stream>>>(stats, gamma, beta, bnp);
    lif_kernel<<<B_ * (CINH_ / 64), 64, 0, stream>>>(h, bnp, sT);
    conv_out_kernel<<<(B_ * T_ / 128) * (COUT_ / 128), 256, 0, stream>>>(xhi, sT, Kee, Koi, bias, out);
}